// Round 1
// baseline (491.825 us; speedup 1.0000x reference)
//
#include <hip/hip_runtime.h>
#include <hip/hip_bf16.h>

#define N_NODES 50000
#define DIM 256
#define N_EDGES 1600000

typedef float f32x4 __attribute__((ext_vector_type(4)));
typedef __bf16 bf16x8 __attribute__((ext_vector_type(8)));
typedef __bf16 bf16x4 __attribute__((ext_vector_type(4)));

// ---------------- W -> bf16 ----------------
__global__ void convw_k(const float* __restrict__ W, __bf16* __restrict__ Wbf) {
    int i = blockIdx.x * blockDim.x + threadIdx.x;
    if (i < DIM * DIM) Wbf[i] = (__bf16)W[i];
}

// ---------------- Y = feature @ W.T  (bf16 MFMA, no LDS) ----------------
// block = 256 threads = 4 waves; wave w computes rows [blk*64 + w*16, +16) x all 256 cols
__global__ __launch_bounds__(256) void gemm_y(const float* __restrict__ feat,
                                              const __bf16* __restrict__ Wbf,
                                              __bf16* __restrict__ Ybf) {
    const int wid  = threadIdx.x >> 6;
    const int lane = threadIdx.x & 63;
    const int row0 = blockIdx.x * 64 + wid * 16;
    const int mrow = lane & 15;
    const int kgrp = lane >> 4;          // 0..3

    int arow = row0 + mrow;
    int arow_c = arow < N_NODES ? arow : (N_NODES - 1);
    const float* aptr = feat + (size_t)arow_c * DIM + kgrp * 8;

    f32x4 acc[16];
#pragma unroll
    for (int i = 0; i < 16; ++i) acc[i] = (f32x4)0.0f;

#pragma unroll
    for (int ks = 0; ks < 8; ++ks) {
        const float* ap = aptr + ks * 32;
        f32x4 a0 = *(const f32x4*)(ap);
        f32x4 a1 = *(const f32x4*)(ap + 4);
        bf16x8 af;
        af[0] = (__bf16)a0[0]; af[1] = (__bf16)a0[1];
        af[2] = (__bf16)a0[2]; af[3] = (__bf16)a0[3];
        af[4] = (__bf16)a1[0]; af[5] = (__bf16)a1[1];
        af[6] = (__bf16)a1[2]; af[7] = (__bf16)a1[3];
#pragma unroll
        for (int nt = 0; nt < 16; ++nt) {
            int ncol = nt * 16 + mrow;   // B col for this lane
            const bf16x8 bf = *(const bf16x8*)(Wbf + (size_t)ncol * DIM + ks * 32 + kgrp * 8);
            acc[nt] = __builtin_amdgcn_mfma_f32_16x16x32_bf16(af, bf, acc[nt], 0, 0, 0);
        }
    }

    // C/D layout (m89): col = lane&15, row = (lane>>4)*4 + reg
    int crow_base = row0 + kgrp * 4;
#pragma unroll
    for (int r = 0; r < 4; ++r) {
        int crow = crow_base + r;
        if (crow < N_NODES) {
            __bf16* yp = Ybf + (size_t)crow * DIM + mrow;
#pragma unroll
            for (int nt = 0; nt < 16; ++nt)
                yp[nt * 16] = (__bf16)acc[nt][r];
        }
    }
}

// ---------------- degree histogram ----------------
__global__ void hist_k(const int* __restrict__ dst, int* __restrict__ deg) {
    int e = blockIdx.x * blockDim.x + threadIdx.x;
    if (e < N_EDGES) atomicAdd(&deg[dst[e]], 1);
}

// ---------------- exclusive scan over 50000 degrees (single block) ----------------
#define SCAN_T 1024
#define CHUNK 49   // 1024*49 = 50176 >= 50000
__global__ __launch_bounds__(SCAN_T) void scan_k(const int* __restrict__ deg,
                                                 int* __restrict__ offsets,
                                                 int* __restrict__ cursor) {
    __shared__ int part[SCAN_T];
    int tid = threadIdx.x;
    int base = tid * CHUNK;
    int sum = 0;
    for (int i = 0; i < CHUNK; ++i) {
        int idx = base + i;
        if (idx < N_NODES) sum += deg[idx];
    }
    part[tid] = sum;
    __syncthreads();
    for (int off = 1; off < SCAN_T; off <<= 1) {
        int v = (tid >= off) ? part[tid - off] : 0;
        __syncthreads();
        part[tid] += v;
        __syncthreads();
    }
    int run = part[tid] - sum;   // exclusive prefix of this thread's chunk
    for (int i = 0; i < CHUNK; ++i) {
        int idx = base + i;
        if (idx < N_NODES) {
            offsets[idx] = run;
            cursor[idx]  = run;
            run += deg[idx];
        }
    }
    if (tid == SCAN_T - 1) offsets[N_NODES] = part[SCAN_T - 1];
}

// ---------------- scatter edge ids into CSR ----------------
__global__ void scatter_k(const int* __restrict__ src, const int* __restrict__ dst,
                          int* __restrict__ cursor, int* __restrict__ edge_src) {
    int e = blockIdx.x * blockDim.x + threadIdx.x;
    if (e < N_EDGES) {
        int pos = atomicAdd(&cursor[dst[e]], 1);
        edge_src[pos] = src[e];
    }
}

// ---------------- per-node gather-mean + bias ----------------
// 1 wave per node; lane owns 4 consecutive columns
__global__ __launch_bounds__(256) void aggregate_k(const __bf16* __restrict__ Ybf,
                                                   const int* __restrict__ offsets,
                                                   const int* __restrict__ edge_src,
                                                   const float* __restrict__ bias,
                                                   float* __restrict__ out) {
    int node = blockIdx.x * 4 + (threadIdx.x >> 6);
    if (node >= N_NODES) return;
    int lane = threadIdx.x & 63;
    int c0 = lane * 4;

    int beg = offsets[node];
    int end = offsets[node + 1];
    float a0 = 0.f, a1 = 0.f, a2 = 0.f, a3 = 0.f;

    int j = beg;
    for (; j + 1 < end; j += 2) {
        int s0 = edge_src[j];
        int s1 = edge_src[j + 1];
        bf16x4 v0 = *(const bf16x4*)(Ybf + (size_t)s0 * DIM + c0);
        bf16x4 v1 = *(const bf16x4*)(Ybf + (size_t)s1 * DIM + c0);
        a0 += (float)v0[0] + (float)v1[0];
        a1 += (float)v0[1] + (float)v1[1];
        a2 += (float)v0[2] + (float)v1[2];
        a3 += (float)v0[3] + (float)v1[3];
    }
    if (j < end) {
        int s0 = edge_src[j];
        bf16x4 v0 = *(const bf16x4*)(Ybf + (size_t)s0 * DIM + c0);
        a0 += (float)v0[0];
        a1 += (float)v0[1];
        a2 += (float)v0[2];
        a3 += (float)v0[3];
    }

    int deg = end - beg;
    f32x4 bv = *(const f32x4*)(bias + c0);
    f32x4 r;
    if (deg > 0) {
        float inv = 1.0f / (float)deg;
        r[0] = a0 * inv + bv[0];
        r[1] = a1 * inv + bv[1];
        r[2] = a2 * inv + bv[2];
        r[3] = a3 * inv + bv[3];
    } else {
        bf16x4 v = *(const bf16x4*)(Ybf + (size_t)node * DIM + c0);
        r[0] = (float)v[0] + bv[0];
        r[1] = (float)v[1] + bv[1];
        r[2] = (float)v[2] + bv[2];
        r[3] = (float)v[3] + bv[3];
    }
    *(f32x4*)(out + (size_t)node * DIM + c0) = r;
}

extern "C" void kernel_launch(void* const* d_in, const int* in_sizes, int n_in,
                              void* d_out, int out_size, void* d_ws, size_t ws_size,
                              hipStream_t stream) {
    const float* feature = (const float*)d_in[0];
    const int*   src     = (const int*)d_in[1];
    const int*   dst     = (const int*)d_in[2];
    const float* W       = (const float*)d_in[3];
    const float* b       = (const float*)d_in[4];
    float* out = (float*)d_out;

    // workspace layout (~32.8 MB total)
    char* ws = (char*)d_ws;
    __bf16* Ybf = (__bf16*)ws;            ws += (size_t)N_NODES * DIM * 2;
    __bf16* Wbf = (__bf16*)ws;            ws += (size_t)DIM * DIM * 2;
    int* deg      = (int*)ws;             ws += (size_t)N_NODES * 4;
    int* offsets  = (int*)ws;             ws += (size_t)(N_NODES + 1) * 4;
    int* cursor   = (int*)ws;             ws += (size_t)N_NODES * 4;
    int* edge_src = (int*)ws;             ws += (size_t)N_EDGES * 4;

    hipMemsetAsync(deg, 0, (size_t)N_NODES * 4, stream);

    convw_k<<<(DIM * DIM + 255) / 256, 256, 0, stream>>>(W, Wbf);
    gemm_y<<<(N_NODES + 63) / 64, 256, 0, stream>>>(feature, Wbf, Ybf);
    hist_k<<<(N_EDGES + 255) / 256, 256, 0, stream>>>(dst, deg);
    scan_k<<<1, SCAN_T, 0, stream>>>(deg, offsets, cursor);
    scatter_k<<<(N_EDGES + 255) / 256, 256, 0, stream>>>(src, dst, cursor, edge_src);
    aggregate_k<<<(N_NODES + 3) / 4, 256, 0, stream>>>(Ybf, offsets, edge_src, b, out);
}